// Round 7
// baseline (221.026 us; speedup 1.0000x reference)
//
#include <hip/hip_runtime.h>
#include <hip/hip_bf16.h>

#define ALPHA2 0.04f   // leaky(leaky(x)) slope for x<0: 0.2*0.2
#define LDA 136        // bf16 row stride in LDS (128 + 8 pad -> conflict-free b128)

typedef __attribute__((ext_vector_type(8))) short short8;
typedef __attribute__((ext_vector_type(4))) float floatx4;
typedef __attribute__((ext_vector_type(8))) unsigned short ushort8;

// ---- bf16 helpers (raw round-to-nearest-even; values are finite) ----
__device__ __forceinline__ unsigned short f2bf(float f) {
    unsigned u = __float_as_uint(f);
    unsigned r = (u + 0x7fffu + ((u >> 16) & 1u)) >> 16;
    return (unsigned short)r;
}
__device__ __forceinline__ float bf2f(unsigned short h) {
    return __uint_as_float((unsigned)h << 16);
}

// NOTE on layout: Pb/Qb/Rb rows are stored with a fixed column permutation
//   c' = (c & 15)*8 + (c >> 4)   (c = canonical col, c' = stored col)
// chosen so each MFMA lane's 8 accumulator values are contiguous -> register-
// direct coalesced ushort8 stores. k_aggregate is elementwise in col, so it
// works in permuted space and un-permutes only bias reads and out writes.

// ---------------- prep: W -> fragment-ordered bf16 Bfr + zero count ---------
// Bfr[((slice*4+kc)*4+quad)*1024 + n*8 + kk] = bf16(W[(slice*128 + kc*32+quad*8+kk)*128 + n])
__global__ void k_prep(const float* __restrict__ W, unsigned short* __restrict__ Bfr,
                       int* __restrict__ count, int NE) {
    int idx = blockIdx.x * blockDim.x + threadIdx.x;
    if (idx < 3 * 128 * 128) {
        int kk = idx & 7, n = (idx >> 3) & 127, g = idx >> 10;
        int slice = g >> 4, kc = (g >> 2) & 3, quad = g & 3;
        int k = kc * 32 + quad * 8 + kk;
        Bfr[idx] = f2bf(W[(size_t)(slice * 128 + k) * 128 + n]);
    }
    if (idx < NE) count[idx] = 0;
}

// ---------------- fused MFMA GEMM: ent@W1->Pb(+s1), ent@W3->Qb(+s3),
//                  rel@W2->Rb(+s2). One A-stage, 1-2 phases, ONE barrier. ----
__global__ __launch_bounds__(256, 4) void k_gemm_all(
        const float* __restrict__ ent, const float* __restrict__ rel,
        const unsigned short* __restrict__ Bfr,
        unsigned short* __restrict__ Pb, unsigned short* __restrict__ Qb,
        unsigned short* __restrict__ Rb,
        float* __restrict__ s1, float* __restrict__ s3, float* __restrict__ s2,
        const float* __restrict__ avec, int NE, int NR, int NBent) {
    __shared__ unsigned short Ash[128 * LDA];
    int tid = threadIdx.x;
    int b = blockIdx.x;
    bool isEnt = b < NBent;
    const float* In = isEnt ? ent : rel;
    int nrows = isEnt ? NE : NR;
    int rowbase = (isEnt ? b : b - NBent) * 128;

    // stage A: 128 rows x 32 chunks of 4 fp32, cast to bf16 (coalesced)
    #pragma unroll
    for (int it = 0; it < 16; ++it) {
        int id = it * 256 + tid;            // 0..4095
        int chunk = id & 31, row = id >> 5;
        int grow = rowbase + row;
        if (grow > nrows - 1) grow = nrows - 1;  // clamp: garbage rows masked at store
        float4 v = *(const float4*)(In + (size_t)grow * 128 + chunk * 4);
        ushort4 u = make_ushort4(f2bf(v.x), f2bf(v.y), f2bf(v.z), f2bf(v.w));
        *(ushort4*)(Ash + row * LDA + chunk * 4) = u;
    }
    __syncthreads();   // the only barrier: Ash is read-only afterwards

    int wave = tid >> 6, lane = tid & 63;
    int m16 = lane & 15, quad = lane >> 4;
    int rs = wave * 32;

    float av[8];
    #pragma unroll
    for (int j = 0; j < 8; ++j) av[j] = avec[j * 16 + m16];

    int nphase = isEnt ? 2 : 1;
    for (int ph = 0; ph < nphase; ++ph) {
        int slice; unsigned short* Out; float* svec;
        if (isEnt) { slice = ph ? 2 : 0; Out = ph ? Qb : Pb; svec = ph ? s3 : s1; }
        else       { slice = 1; Out = Rb; svec = s2; }

        floatx4 acc[2][8];
        #pragma unroll
        for (int i = 0; i < 2; ++i)
            #pragma unroll
            for (int j = 0; j < 8; ++j) acc[i][j] = (floatx4){0.f, 0.f, 0.f, 0.f};

        #pragma unroll
        for (int kc = 0; kc < 4; ++kc) {
            // B fragments: coalesced 16B loads from L2-resident Bfr
            const unsigned short* bb = Bfr + (size_t)((slice * 4 + kc) * 4 + quad) * 1024 + m16 * 8;
            short8 bf[8], af[2];
            #pragma unroll
            for (int j = 0; j < 8; ++j) bf[j] = *(const short8*)(bb + j * 128);
            #pragma unroll
            for (int i = 0; i < 2; ++i)
                af[i] = *(const short8*)(Ash + (rs + i * 16 + m16) * LDA + kc * 32 + quad * 8);
            #pragma unroll
            for (int i = 0; i < 2; ++i)
                #pragma unroll
                for (int j = 0; j < 8; ++j)
                    acc[i][j] = __builtin_amdgcn_mfma_f32_16x16x32_bf16(af[i], bf[j], acc[i][j], 0, 0, 0);
        }

        // epilogue: register-direct permuted store + fused svec = row·avec
        // (C/D layout: canonical col=j*16+m16, row=quad*4+reg; permuted col=m16*8+j)
        #pragma unroll
        for (int i = 0; i < 2; ++i) {
            #pragma unroll
            for (int reg = 0; reg < 4; ++reg) {
                int row = rowbase + rs + i * 16 + quad * 4 + reg;
                float part = 0.f;
                ushort8 v;
                #pragma unroll
                for (int j = 0; j < 8; ++j) {
                    float x = acc[i][j][reg];
                    part = fmaf(x, av[j], part);
                    v[j] = f2bf(x);
                }
                #pragma unroll
                for (int off = 1; off < 16; off <<= 1) part += __shfl_xor(part, off);
                if (row < nrows) {
                    *(ushort8*)(Out + (size_t)row * 128 + m16 * 8) = v;
                    if (m16 == 0) svec[row] = part;
                }
            }
        }
    }
}

// ---------------- edge pass 1: degree count + per-edge rank ----------------
__global__ void k_count(const int* __restrict__ h, int* __restrict__ count,
                        int* __restrict__ rank, int E) {
    int e = blockIdx.x * blockDim.x + threadIdx.x;
    if (e < E) rank[e] = atomicAdd(count + h[e], 1);
}

// ---------------- hierarchical exclusive scan of count -> rowstart ----------
__device__ __forceinline__ int block_incl_scan256(int s, int* sh, int t) {
    sh[t] = s; __syncthreads();
    #pragma unroll
    for (int off = 1; off < 256; off <<= 1) {
        int x = 0;
        if (t >= off) x = sh[t - off];
        __syncthreads();
        sh[t] += x;
        __syncthreads();
    }
    return sh[t];
}

__global__ __launch_bounds__(256) void k_scan_a(const int* __restrict__ count, int NE,
                                                int* __restrict__ bsum) {
    __shared__ int sh[256];
    int b = blockIdx.x, t = threadIdx.x;
    int base = b * 1024 + t * 4, s = 0;
    #pragma unroll
    for (int j = 0; j < 4; ++j) { int i = base + j; if (i < NE) s += count[i]; }
    sh[t] = s; __syncthreads();
    for (int off = 128; off > 0; off >>= 1) {
        if (t < off) sh[t] += sh[t + off];
        __syncthreads();
    }
    if (t == 0) bsum[b] = sh[0];
}

__global__ __launch_bounds__(256) void k_scan_b(int* __restrict__ bsum, int NB) {
    __shared__ int sh[256];
    int t = threadIdx.x;
    int v[4]; int s = 0;
    #pragma unroll
    for (int j = 0; j < 4; ++j) { int i = t * 4 + j; v[j] = (i < NB) ? bsum[i] : 0; s += v[j]; }
    int incl = block_incl_scan256(s, sh, t);
    int excl = incl - s;
    #pragma unroll
    for (int j = 0; j < 4; ++j) {
        int i = t * 4 + j;
        if (i < NB) { int tmp = v[j]; bsum[i] = excl; excl += tmp; }
    }
}

__global__ __launch_bounds__(256) void k_scan_c(const int* __restrict__ count, int NE,
                                                const int* __restrict__ bsum,
                                                int* __restrict__ rowstart, int E) {
    __shared__ int sh[256];
    int b = blockIdx.x, t = threadIdx.x;
    int base = b * 1024 + t * 4;
    int v[4]; int s = 0;
    #pragma unroll
    for (int j = 0; j < 4; ++j) { int i = base + j; v[j] = (i < NE) ? count[i] : 0; s += v[j]; }
    int incl = block_incl_scan256(s, sh, t);
    int excl = bsum[b] + incl - s;
    #pragma unroll
    for (int j = 0; j < 4; ++j) {
        int i = base + j;
        if (i < NE) { rowstart[i] = excl; excl += v[j]; }
    }
    if (b == 0 && t == 0) rowstart[NE] = E;
}

// ---------------- edge pass 2: score -> exp -> CSR scatter {(r<<17)|t, ev} --
// Atomic-free: rank precomputed in pass 1. No max shift (|score| <~ 6, fp32
// exp safe; softmax shift-invariant). t < 2^17 (NE=100k), r < 2^10 (NR=1000).
__global__ void k_score_scatter(const int* __restrict__ h, const int* __restrict__ r,
                                const int* __restrict__ t, const float* __restrict__ s1,
                                const float* __restrict__ s2, const float* __restrict__ s3,
                                const float* __restrict__ a_b,
                                const int* __restrict__ rowstart, const int* __restrict__ rank,
                                uint2* __restrict__ rt_s, int E) {
    int e = blockIdx.x * blockDim.x + threadIdx.x;
    if (e >= E) return;
    int hi = h[e], ri = r[e], ti = t[e];
    float x = s1[hi] + s2[ri] + s3[ti] + a_b[0];
    float sc = (x >= 0.f) ? x : ALPHA2 * x;
    float ev = __expf(sc);
    rt_s[rowstart[hi] + rank[e]] = make_uint2(((unsigned)ri << 17) | (unsigned)ti,
                                              __float_as_uint(ev));
}

// ---------------- per-entity aggregation: 16 lanes per entity ---------------
// Works in permuted-column space (Pb/Qb/Rb all share the permutation); only
// bias reads and out writes go through the inverse permutation.
__global__ __launch_bounds__(256) void k_aggregate(const int* __restrict__ rowstart,
                                                   const uint2* __restrict__ rt_s,
                                                   const unsigned short* __restrict__ Pb,
                                                   const unsigned short* __restrict__ Qb,
                                                   const unsigned short* __restrict__ Rb,
                                                   const float* __restrict__ bias,
                                                   float* __restrict__ out, int NE) {
    int gid = blockIdx.x * blockDim.x + threadIdx.x;
    int n = gid >> 4;        // entity
    int sl = gid & 15;       // sublane: covers permuted cols sl*8..sl*8+7
    if (n >= NE) return;
    int start = rowstart[n], end = rowstart[n + 1];
    int c0 = sl * 8;
    float acc[8] = {};
    float evsum = 0.f;
    int i = start;
    for (; i + 2 <= end; i += 2) {
        uint2 m0 = rt_s[i], m1 = rt_s[i + 1];
        float ev0 = __uint_as_float(m0.y), ev1 = __uint_as_float(m1.y);
        unsigned t0 = m0.x & 0x1FFFFu, r0 = m0.x >> 17;
        unsigned t1 = m1.x & 0x1FFFFu, r1 = m1.x >> 17;
        ushort8 q0 = *(const ushort8*)(Qb + (size_t)t0 * 128 + c0);
        ushort8 rr0 = *(const ushort8*)(Rb + (size_t)r0 * 128 + c0);
        ushort8 q1 = *(const ushort8*)(Qb + (size_t)t1 * 128 + c0);
        ushort8 rr1 = *(const ushort8*)(Rb + (size_t)r1 * 128 + c0);
        evsum += ev0 + ev1;
        #pragma unroll
        for (int j = 0; j < 8; ++j)
            acc[j] = fmaf(ev0, bf2f(q0[j]) + bf2f(rr0[j]), acc[j]);
        #pragma unroll
        for (int j = 0; j < 8; ++j)
            acc[j] = fmaf(ev1, bf2f(q1[j]) + bf2f(rr1[j]), acc[j]);
    }
    if (i < end) {
        uint2 m0 = rt_s[i];
        float ev0 = __uint_as_float(m0.y);
        unsigned t0 = m0.x & 0x1FFFFu, r0 = m0.x >> 17;
        ushort8 q0 = *(const ushort8*)(Qb + (size_t)t0 * 128 + c0);
        ushort8 rr0 = *(const ushort8*)(Rb + (size_t)r0 * 128 + c0);
        evsum += ev0;
        #pragma unroll
        for (int j = 0; j < 8; ++j)
            acc[j] = fmaf(ev0, bf2f(q0[j]) + bf2f(rr0[j]), acc[j]);
    }
    // inverse permutation: stored col sl*8+j  <->  canonical col j*16+sl
    float bi[8];
    #pragma unroll
    for (int j = 0; j < 8; ++j) bi[j] = bias[j * 16 + sl];
    float o[8];
    if (end > start) {
        float inv = 1.f / evsum;
        ushort8 pb = *(const ushort8*)(Pb + (size_t)n * 128 + c0);
        #pragma unroll
        for (int j = 0; j < 8; ++j) o[j] = bf2f(pb[j]) + acc[j] * inv + bi[j];
    } else {
        #pragma unroll
        for (int j = 0; j < 8; ++j) o[j] = bi[j];
    }
    #pragma unroll
    for (int j = 0; j < 8; ++j)
        out[(size_t)n * 128 + j * 16 + sl] = fmaxf(o[j], 0.f);
}

// ============================================================================
static inline size_t align_up(size_t x, size_t a) { return (x + a - 1) / a * a; }

extern "C" void kernel_launch(void* const* d_in, const int* in_sizes, int n_in,
                              void* d_out, int out_size, void* d_ws, size_t ws_size,
                              hipStream_t stream) {
    const int* h_index = (const int*)d_in[0];
    const int* r_index = (const int*)d_in[1];
    const int* t_index = (const int*)d_in[2];
    const float* ent = (const float*)d_in[3];
    const float* rel = (const float*)d_in[4];
    const float* W = (const float*)d_in[5];
    const float* a = (const float*)d_in[6];
    const float* a_b = (const float*)d_in[7];
    const float* bias = (const float*)d_in[8];
    float* out = (float*)d_out;

    int E = in_sizes[0];
    int NE = in_sizes[3] / 128;
    int NR = in_sizes[4] / 128;

    char* p = (char*)d_ws;
    auto alloc = [&](size_t bytes) { char* q = p; p += align_up(bytes, 256); return (void*)q; };
    unsigned short* Pb = (unsigned short*)alloc((size_t)NE * 128 * 2);
    unsigned short* Qb = (unsigned short*)alloc((size_t)NE * 128 * 2);
    unsigned short* Rb = (unsigned short*)alloc((size_t)NR * 128 * 2);
    unsigned short* Bfr = (unsigned short*)alloc((size_t)3 * 128 * 128 * 2);
    float* s1 = (float*)alloc((size_t)NE * 4);
    float* s3 = (float*)alloc((size_t)NE * 4);
    float* s2 = (float*)alloc((size_t)NR * 4);
    int* count = (int*)alloc((size_t)NE * 4);
    int* rowstart = (int*)alloc((size_t)(NE + 1) * 4);
    int* rank = (int*)alloc((size_t)E * 4);
    int NB = (NE + 1023) / 1024;
    int* bsum = (int*)alloc((size_t)NB * 4);
    uint2* rt_s = (uint2*)alloc((size_t)E * 8);
    (void)ws_size; (void)n_in; (void)out_size;

    // 1. prep: W -> fragment-ordered bf16 + zero counters
    int nprep = (NE > 3 * 128 * 128) ? NE : 3 * 128 * 128;
    k_prep<<<(nprep + 255) / 256, 256, 0, stream>>>(W, Bfr, count, NE);
    // 2. edge pass 1: degree count + rank (independent of GEMMs)
    k_count<<<(E + 255) / 256, 256, 0, stream>>>(h_index, count, rank, E);
    // 3. all three GEMMs in one dispatch
    int NBent = (NE + 127) / 128, NBrel = (NR + 127) / 128;
    k_gemm_all<<<NBent + NBrel, 256, 0, stream>>>(ent, rel, Bfr, Pb, Qb, Rb,
                                                  s1, s3, s2, a, NE, NR, NBent);
    // 4-6. scan -> rowstart
    k_scan_a<<<NB, 256, 0, stream>>>(count, NE, bsum);
    k_scan_b<<<1, 256, 0, stream>>>(bsum, NB);
    k_scan_c<<<NB, 256, 0, stream>>>(count, NE, bsum, rowstart, E);
    // 7. edge pass 2: score -> exp -> CSR scatter (atomic-free, packed 8B)
    k_score_scatter<<<(E + 255) / 256, 256, 0, stream>>>(h_index, r_index, t_index,
                                                         s1, s2, s3, a_b, rowstart,
                                                         rank, rt_s, E);
    // 8. aggregate + bias + relu (16 lanes/entity, denom in-register)
    k_aggregate<<<(NE * 16 + 255) / 256, 256, 0, stream>>>(rowstart, rt_s, Pb, Qb, Rb,
                                                           bias, out, NE);
}

// Round 8
// 218.813 us; speedup vs baseline: 1.0101x; 1.0101x over previous
//
#include <hip/hip_runtime.h>
#include <hip/hip_bf16.h>

#define ALPHA2 0.04f   // leaky(leaky(x)) slope for x<0: 0.2*0.2
#define LDA 136        // bf16 row stride in LDS (128 + 8 pad -> conflict-free b128)

typedef __attribute__((ext_vector_type(8))) short short8;
typedef __attribute__((ext_vector_type(4))) float floatx4;
typedef __attribute__((ext_vector_type(8))) unsigned short ushort8;

// ---- bf16 helpers (raw round-to-nearest-even; values are finite) ----
__device__ __forceinline__ unsigned short f2bf(float f) {
    unsigned u = __float_as_uint(f);
    unsigned r = (u + 0x7fffu + ((u >> 16) & 1u)) >> 16;
    return (unsigned short)r;
}
__device__ __forceinline__ float bf2f(unsigned short h) {
    return __uint_as_float((unsigned)h << 16);
}

// NOTE on layout: Pb/Qb/Rb rows are stored with a fixed column permutation
//   c' = (c & 15)*8 + (c >> 4)   (c = canonical col, c' = stored col)
// chosen so each MFMA lane's 8 accumulator values are contiguous -> register-
// direct coalesced ushort8 stores. k_aggregate is elementwise in col, so it
// works in permuted space and un-permutes only bias reads and out writes.

// ---------------- prep: W -> fragment-ordered bf16 Bfr + zero count ---------
// Bfr[((slice*4+kc)*4+quad)*1024 + n*8 + kk] = bf16(W[(slice*128 + kc*32+quad*8+kk)*128 + n])
__global__ void k_prep(const float* __restrict__ W, unsigned short* __restrict__ Bfr,
                       int* __restrict__ count, int NE) {
    int idx = blockIdx.x * blockDim.x + threadIdx.x;
    if (idx < 3 * 128 * 128) {
        int kk = idx & 7, n = (idx >> 3) & 127, g = idx >> 10;
        int slice = g >> 4, kc = (g >> 2) & 3, quad = g & 3;
        int k = kc * 32 + quad * 8 + kk;
        Bfr[idx] = f2bf(W[(size_t)(slice * 128 + k) * 128 + n]);
    }
    if (idx < NE) count[idx] = 0;
}

// ---------------- fused MFMA GEMM: ent@W1->Pb(+s1), ent@W3->Qb(+s3),
// rel@W2->Rb(+s2). 64-row blocks (one 16-row strip per wave) for high
// block-level overlap; B fragments straight from L2-resident Bfr. ----------
__global__ __launch_bounds__(256, 6) void k_gemm_all(
        const float* __restrict__ ent, const float* __restrict__ rel,
        const unsigned short* __restrict__ Bfr,
        unsigned short* __restrict__ Pb, unsigned short* __restrict__ Qb,
        unsigned short* __restrict__ Rb,
        float* __restrict__ s1, float* __restrict__ s3, float* __restrict__ s2,
        const float* __restrict__ avec, int NE, int NR, int NBent) {
    __shared__ unsigned short Ash[64 * LDA];
    int tid = threadIdx.x;
    int b = blockIdx.x;
    bool isEnt = b < NBent;
    const float* In = isEnt ? ent : rel;
    int nrows = isEnt ? NE : NR;
    int rowbase = (isEnt ? b : b - NBent) * 64;

    // stage A: 64 rows x 32 chunks of 4 fp32, cast to bf16 (coalesced)
    #pragma unroll
    for (int it = 0; it < 8; ++it) {
        int id = it * 256 + tid;            // 0..2047
        int chunk = id & 31, row = id >> 5;
        int grow = rowbase + row;
        if (grow > nrows - 1) grow = nrows - 1;  // clamp: garbage rows masked at store
        float4 v = *(const float4*)(In + (size_t)grow * 128 + chunk * 4);
        ushort4 u = make_ushort4(f2bf(v.x), f2bf(v.y), f2bf(v.z), f2bf(v.w));
        *(ushort4*)(Ash + row * LDA + chunk * 4) = u;
    }
    __syncthreads();   // the only barrier: Ash is read-only afterwards

    int wave = tid >> 6, lane = tid & 63;
    int m16 = lane & 15, quad = lane >> 4;
    int rs = wave * 16;

    float av[8];
    #pragma unroll
    for (int j = 0; j < 8; ++j) av[j] = avec[j * 16 + m16];

    int nphase = isEnt ? 2 : 1;
    for (int ph = 0; ph < nphase; ++ph) {
        int slice; unsigned short* Out; float* svec;
        if (isEnt) { slice = ph ? 2 : 0; Out = ph ? Qb : Pb; svec = ph ? s3 : s1; }
        else       { slice = 1; Out = Rb; svec = s2; }

        floatx4 acc[8];
        #pragma unroll
        for (int j = 0; j < 8; ++j) acc[j] = (floatx4){0.f, 0.f, 0.f, 0.f};

        #pragma unroll
        for (int kc = 0; kc < 4; ++kc) {
            // B fragments: coalesced 16B loads from L2-resident Bfr
            const unsigned short* bb = Bfr + (size_t)((slice * 4 + kc) * 4 + quad) * 1024 + m16 * 8;
            short8 bf[8];
            #pragma unroll
            for (int j = 0; j < 8; ++j) bf[j] = *(const short8*)(bb + j * 128);
            short8 af = *(const short8*)(Ash + (rs + m16) * LDA + kc * 32 + quad * 8);
            #pragma unroll
            for (int j = 0; j < 8; ++j)
                acc[j] = __builtin_amdgcn_mfma_f32_16x16x32_bf16(af, bf[j], acc[j], 0, 0, 0);
        }

        // epilogue: register-direct permuted store + fused svec = row·avec
        // (C/D layout: canonical col=j*16+m16, row=quad*4+reg; permuted col=m16*8+j)
        #pragma unroll
        for (int reg = 0; reg < 4; ++reg) {
            int row = rowbase + rs + quad * 4 + reg;
            float part = 0.f;
            ushort8 v;
            #pragma unroll
            for (int j = 0; j < 8; ++j) {
                float x = acc[j][reg];
                part = fmaf(x, av[j], part);
                v[j] = f2bf(x);
            }
            #pragma unroll
            for (int off = 1; off < 16; off <<= 1) part += __shfl_xor(part, off);
            if (row < nrows) {
                *(ushort8*)(Out + (size_t)row * 128 + m16 * 8) = v;
                if (m16 == 0) svec[row] = part;
            }
        }
    }
}

// ---------------- edge pass 1: degree count + per-edge rank ----------------
__global__ void k_count(const int* __restrict__ h, int* __restrict__ count,
                        int* __restrict__ rank, int E) {
    int e = blockIdx.x * blockDim.x + threadIdx.x;
    if (e < E) rank[e] = atomicAdd(count + h[e], 1);
}

// ---------------- hierarchical exclusive scan of count -> rowstart ----------
__device__ __forceinline__ int block_incl_scan256(int s, int* sh, int t) {
    sh[t] = s; __syncthreads();
    #pragma unroll
    for (int off = 1; off < 256; off <<= 1) {
        int x = 0;
        if (t >= off) x = sh[t - off];
        __syncthreads();
        sh[t] += x;
        __syncthreads();
    }
    return sh[t];
}

__global__ __launch_bounds__(256) void k_scan_a(const int* __restrict__ count, int NE,
                                                int* __restrict__ bsum) {
    __shared__ int sh[256];
    int b = blockIdx.x, t = threadIdx.x;
    int base = b * 1024 + t * 4, s = 0;
    #pragma unroll
    for (int j = 0; j < 4; ++j) { int i = base + j; if (i < NE) s += count[i]; }
    sh[t] = s; __syncthreads();
    for (int off = 128; off > 0; off >>= 1) {
        if (t < off) sh[t] += sh[t + off];
        __syncthreads();
    }
    if (t == 0) bsum[b] = sh[0];
}

__global__ __launch_bounds__(256) void k_scan_b(int* __restrict__ bsum, int NB) {
    __shared__ int sh[256];
    int t = threadIdx.x;
    int v[4]; int s = 0;
    #pragma unroll
    for (int j = 0; j < 4; ++j) { int i = t * 4 + j; v[j] = (i < NB) ? bsum[i] : 0; s += v[j]; }
    int incl = block_incl_scan256(s, sh, t);
    int excl = incl - s;
    #pragma unroll
    for (int j = 0; j < 4; ++j) {
        int i = t * 4 + j;
        if (i < NB) { int tmp = v[j]; bsum[i] = excl; excl += tmp; }
    }
}

__global__ __launch_bounds__(256) void k_scan_c(const int* __restrict__ count, int NE,
                                                const int* __restrict__ bsum,
                                                int* __restrict__ rowstart, int E) {
    __shared__ int sh[256];
    int b = blockIdx.x, t = threadIdx.x;
    int base = b * 1024 + t * 4;
    int v[4]; int s = 0;
    #pragma unroll
    for (int j = 0; j < 4; ++j) { int i = base + j; v[j] = (i < NE) ? count[i] : 0; s += v[j]; }
    int incl = block_incl_scan256(s, sh, t);
    int excl = bsum[b] + incl - s;
    #pragma unroll
    for (int j = 0; j < 4; ++j) {
        int i = base + j;
        if (i < NE) { rowstart[i] = excl; excl += v[j]; }
    }
    if (b == 0 && t == 0) rowstart[NE] = E;
}

// ---------------- edge pass 2: score -> exp -> CSR scatter {(r<<17)|t, ev} --
// Atomic-free: rank precomputed in pass 1. No max shift (|score| <~ 6, fp32
// exp safe; softmax shift-invariant). t < 2^17 (NE=100k), r < 2^10 (NR=1000).
__global__ void k_score_scatter(const int* __restrict__ h, const int* __restrict__ r,
                                const int* __restrict__ t, const float* __restrict__ s1,
                                const float* __restrict__ s2, const float* __restrict__ s3,
                                const float* __restrict__ a_b,
                                const int* __restrict__ rowstart, const int* __restrict__ rank,
                                uint2* __restrict__ rt_s, int E) {
    int e = blockIdx.x * blockDim.x + threadIdx.x;
    if (e >= E) return;
    int hi = h[e], ri = r[e], ti = t[e];
    float x = s1[hi] + s2[ri] + s3[ti] + a_b[0];
    float sc = (x >= 0.f) ? x : ALPHA2 * x;
    float ev = __expf(sc);
    rt_s[rowstart[hi] + rank[e]] = make_uint2(((unsigned)ri << 17) | (unsigned)ti,
                                              __float_as_uint(ev));
}

// ---------------- per-entity aggregation: 16 lanes per entity ---------------
// Works in permuted-column space (Pb/Qb/Rb all share the permutation); only
// bias reads and out writes go through the inverse permutation.
__global__ __launch_bounds__(256) void k_aggregate(const int* __restrict__ rowstart,
                                                   const uint2* __restrict__ rt_s,
                                                   const unsigned short* __restrict__ Pb,
                                                   const unsigned short* __restrict__ Qb,
                                                   const unsigned short* __restrict__ Rb,
                                                   const float* __restrict__ bias,
                                                   float* __restrict__ out, int NE) {
    int gid = blockIdx.x * blockDim.x + threadIdx.x;
    int n = gid >> 4;        // entity
    int sl = gid & 15;       // sublane: covers permuted cols sl*8..sl*8+7
    if (n >= NE) return;
    int start = rowstart[n], end = rowstart[n + 1];
    int c0 = sl * 8;
    float acc[8] = {};
    float evsum = 0.f;
    int i = start;
    for (; i + 2 <= end; i += 2) {
        uint2 m0 = rt_s[i], m1 = rt_s[i + 1];
        float ev0 = __uint_as_float(m0.y), ev1 = __uint_as_float(m1.y);
        unsigned t0 = m0.x & 0x1FFFFu, r0 = m0.x >> 17;
        unsigned t1 = m1.x & 0x1FFFFu, r1 = m1.x >> 17;
        ushort8 q0 = *(const ushort8*)(Qb + (size_t)t0 * 128 + c0);
        ushort8 rr0 = *(const ushort8*)(Rb + (size_t)r0 * 128 + c0);
        ushort8 q1 = *(const ushort8*)(Qb + (size_t)t1 * 128 + c0);
        ushort8 rr1 = *(const ushort8*)(Rb + (size_t)r1 * 128 + c0);
        evsum += ev0 + ev1;
        #pragma unroll
        for (int j = 0; j < 8; ++j)
            acc[j] = fmaf(ev0, bf2f(q0[j]) + bf2f(rr0[j]), acc[j]);
        #pragma unroll
        for (int j = 0; j < 8; ++j)
            acc[j] = fmaf(ev1, bf2f(q1[j]) + bf2f(rr1[j]), acc[j]);
    }
    if (i < end) {
        uint2 m0 = rt_s[i];
        float ev0 = __uint_as_float(m0.y);
        unsigned t0 = m0.x & 0x1FFFFu, r0 = m0.x >> 17;
        ushort8 q0 = *(const ushort8*)(Qb + (size_t)t0 * 128 + c0);
        ushort8 rr0 = *(const ushort8*)(Rb + (size_t)r0 * 128 + c0);
        evsum += ev0;
        #pragma unroll
        for (int j = 0; j < 8; ++j)
            acc[j] = fmaf(ev0, bf2f(q0[j]) + bf2f(rr0[j]), acc[j]);
    }
    // inverse permutation: stored col sl*8+j  <->  canonical col j*16+sl
    float bi[8];
    #pragma unroll
    for (int j = 0; j < 8; ++j) bi[j] = bias[j * 16 + sl];
    float o[8];
    if (end > start) {
        float inv = 1.f / evsum;
        ushort8 pb = *(const ushort8*)(Pb + (size_t)n * 128 + c0);
        #pragma unroll
        for (int j = 0; j < 8; ++j) o[j] = bf2f(pb[j]) + acc[j] * inv + bi[j];
    } else {
        #pragma unroll
        for (int j = 0; j < 8; ++j) o[j] = bi[j];
    }
    #pragma unroll
    for (int j = 0; j < 8; ++j)
        out[(size_t)n * 128 + j * 16 + sl] = fmaxf(o[j], 0.f);
}

// ============================================================================
static inline size_t align_up(size_t x, size_t a) { return (x + a - 1) / a * a; }

extern "C" void kernel_launch(void* const* d_in, const int* in_sizes, int n_in,
                              void* d_out, int out_size, void* d_ws, size_t ws_size,
                              hipStream_t stream) {
    const int* h_index = (const int*)d_in[0];
    const int* r_index = (const int*)d_in[1];
    const int* t_index = (const int*)d_in[2];
    const float* ent = (const float*)d_in[3];
    const float* rel = (const float*)d_in[4];
    const float* W = (const float*)d_in[5];
    const float* a = (const float*)d_in[6];
    const float* a_b = (const float*)d_in[7];
    const float* bias = (const float*)d_in[8];
    float* out = (float*)d_out;

    int E = in_sizes[0];
    int NE = in_sizes[3] / 128;
    int NR = in_sizes[4] / 128;

    char* p = (char*)d_ws;
    auto alloc = [&](size_t bytes) { char* q = p; p += align_up(bytes, 256); return (void*)q; };
    unsigned short* Pb = (unsigned short*)alloc((size_t)NE * 128 * 2);
    unsigned short* Qb = (unsigned short*)alloc((size_t)NE * 128 * 2);
    unsigned short* Rb = (unsigned short*)alloc((size_t)NR * 128 * 2);
    unsigned short* Bfr = (unsigned short*)alloc((size_t)3 * 128 * 128 * 2);
    float* s1 = (float*)alloc((size_t)NE * 4);
    float* s3 = (float*)alloc((size_t)NE * 4);
    float* s2 = (float*)alloc((size_t)NR * 4);
    int* count = (int*)alloc((size_t)NE * 4);
    int* rowstart = (int*)alloc((size_t)(NE + 1) * 4);
    int* rank = (int*)alloc((size_t)E * 4);
    int NB = (NE + 1023) / 1024;
    int* bsum = (int*)alloc((size_t)NB * 4);
    uint2* rt_s = (uint2*)alloc((size_t)E * 8);
    (void)ws_size; (void)n_in; (void)out_size;

    // 1. prep: W -> fragment-ordered bf16 + zero counters
    int nprep = (NE > 3 * 128 * 128) ? NE : 3 * 128 * 128;
    k_prep<<<(nprep + 255) / 256, 256, 0, stream>>>(W, Bfr, count, NE);
    // 2. edge pass 1: degree count + rank (independent of GEMMs)
    k_count<<<(E + 255) / 256, 256, 0, stream>>>(h_index, count, rank, E);
    // 3. all three GEMMs in one dispatch (64-row tiles)
    int NBent = (NE + 63) / 64, NBrel = (NR + 63) / 64;
    k_gemm_all<<<NBent + NBrel, 256, 0, stream>>>(ent, rel, Bfr, Pb, Qb, Rb,
                                                  s1, s3, s2, a, NE, NR, NBent);
    // 4-6. scan -> rowstart
    k_scan_a<<<NB, 256, 0, stream>>>(count, NE, bsum);
    k_scan_b<<<1, 256, 0, stream>>>(bsum, NB);
    k_scan_c<<<NB, 256, 0, stream>>>(count, NE, bsum, rowstart, E);
    // 7. edge pass 2: score -> exp -> CSR scatter (atomic-free, packed 8B)
    k_score_scatter<<<(E + 255) / 256, 256, 0, stream>>>(h_index, r_index, t_index,
                                                         s1, s2, s3, a_b, rowstart,
                                                         rank, rt_s, E);
    // 8. aggregate + bias + relu (16 lanes/entity, denom in-register)
    k_aggregate<<<(NE * 16 + 255) / 256, 256, 0, stream>>>(rowstart, rt_s, Pb, Qb, Rb,
                                                           bias, out, NE);
}

// Round 9
// 208.803 us; speedup vs baseline: 1.0585x; 1.0479x over previous
//
#include <hip/hip_runtime.h>
#include <hip/hip_bf16.h>

#define ALPHA2 0.04f   // leaky(leaky(x)) slope for x<0: 0.2*0.2
#define LDA 136        // bf16 row stride in LDS (128 + 8 pad -> conflict-free b128)

typedef __attribute__((ext_vector_type(8))) short short8;
typedef __attribute__((ext_vector_type(4))) float floatx4;
typedef __attribute__((ext_vector_type(8))) unsigned short ushort8;

// ---- bf16 helpers (raw round-to-nearest-even; values are finite) ----
__device__ __forceinline__ unsigned short f2bf(float f) {
    unsigned u = __float_as_uint(f);
    unsigned r = (u + 0x7fffu + ((u >> 16) & 1u)) >> 16;
    return (unsigned short)r;
}
__device__ __forceinline__ float bf2f(unsigned short h) {
    return __uint_as_float((unsigned)h << 16);
}

// NOTE on layout: Pb/Qb/Rb rows are stored with a fixed column permutation
//   c' = (c & 15)*8 + (c >> 4)   (c = canonical col, c' = stored col)
// chosen so each MFMA lane's 8 accumulator values are contiguous -> register-
// direct coalesced ushort8 stores. k_aggregate is elementwise in col, so it
// works in permuted space and un-permutes only bias reads and out writes.

// ---------------- prep: W -> fragment-ordered bf16 Bfr + zero count ---------
// Bfr[((slice*4+kc)*4+quad)*1024 + n*8 + kk] = bf16(W[(slice*128 + kc*32+quad*8+kk)*128 + n])
__global__ void k_prep(const float* __restrict__ W, unsigned short* __restrict__ Bfr,
                       int* __restrict__ count, int NE) {
    int idx = blockIdx.x * blockDim.x + threadIdx.x;
    if (idx < 3 * 128 * 128) {
        int kk = idx & 7, n = (idx >> 3) & 127, g = idx >> 10;
        int slice = g >> 4, kc = (g >> 2) & 3, quad = g & 3;
        int k = kc * 32 + quad * 8 + kk;
        Bfr[idx] = f2bf(W[(size_t)(slice * 128 + k) * 128 + n]);
    }
    if (idx < NE) count[idx] = 0;
}

// ---------------- fused MFMA GEMM: ent@W1->Pb(+s1), ent@W3->Qb(+s3),
// rel@W2->Rb(+s2). 64-row blocks, one 16-row strip per wave; B fragments
// from L2-resident Bfr with explicit double-buffering across kc so loads
// of kc+1 are in flight while kc's MFMAs run. ------------------------------
__global__ __launch_bounds__(256, 4) void k_gemm_all(
        const float* __restrict__ ent, const float* __restrict__ rel,
        const unsigned short* __restrict__ Bfr,
        unsigned short* __restrict__ Pb, unsigned short* __restrict__ Qb,
        unsigned short* __restrict__ Rb,
        float* __restrict__ s1, float* __restrict__ s3, float* __restrict__ s2,
        const float* __restrict__ avec, int NE, int NR, int NBent) {
    __shared__ unsigned short Ash[64 * LDA];
    int tid = threadIdx.x;
    int b = blockIdx.x;
    bool isEnt = b < NBent;
    const float* In = isEnt ? ent : rel;
    int nrows = isEnt ? NE : NR;
    int rowbase = (isEnt ? b : b - NBent) * 64;

    // stage A: 64 rows x 32 chunks of 4 fp32, cast to bf16 (coalesced)
    #pragma unroll
    for (int it = 0; it < 8; ++it) {
        int id = it * 256 + tid;            // 0..2047
        int chunk = id & 31, row = id >> 5;
        int grow = rowbase + row;
        if (grow > nrows - 1) grow = nrows - 1;  // clamp: garbage rows masked at store
        float4 v = *(const float4*)(In + (size_t)grow * 128 + chunk * 4);
        ushort4 u = make_ushort4(f2bf(v.x), f2bf(v.y), f2bf(v.z), f2bf(v.w));
        *(ushort4*)(Ash + row * LDA + chunk * 4) = u;
    }
    __syncthreads();   // the only barrier: Ash is read-only afterwards

    int wave = tid >> 6, lane = tid & 63;
    int m16 = lane & 15, quad = lane >> 4;
    int rs = wave * 16;

    float av[8];
    #pragma unroll
    for (int j = 0; j < 8; ++j) av[j] = avec[j * 16 + m16];

    int nphase = isEnt ? 2 : 1;
    for (int ph = 0; ph < nphase; ++ph) {
        int slice; unsigned short* Out; float* svec;
        if (isEnt) { slice = ph ? 2 : 0; Out = ph ? Qb : Pb; svec = ph ? s3 : s1; }
        else       { slice = 1; Out = Rb; svec = s2; }

        floatx4 acc[8];
        #pragma unroll
        for (int j = 0; j < 8; ++j) acc[j] = (floatx4){0.f, 0.f, 0.f, 0.f};

        short8 bf0[8], bf1[8];
        auto loadB = [&](int kc, short8* dst) {
            const unsigned short* bb =
                Bfr + (size_t)((slice * 4 + kc) * 4 + quad) * 1024 + m16 * 8;
            #pragma unroll
            for (int j = 0; j < 8; ++j) dst[j] = *(const short8*)(bb + j * 128);
        };
        auto doMfma = [&](int kc, short8* bf) {
            short8 af = *(const short8*)(Ash + (rs + m16) * LDA + kc * 32 + quad * 8);
            #pragma unroll
            for (int j = 0; j < 8; ++j)
                acc[j] = __builtin_amdgcn_mfma_f32_16x16x32_bf16(af, bf[j], acc[j], 0, 0, 0);
        };
        // hand-pipelined: kc+1 loads in flight under kc's MFMAs
        loadB(0, bf0);
        loadB(1, bf1);
        doMfma(0, bf0);
        loadB(2, bf0);
        doMfma(1, bf1);
        loadB(3, bf1);
        doMfma(2, bf0);
        doMfma(3, bf1);

        // epilogue: register-direct permuted store + fused svec = row·avec
        // (C/D layout: canonical col=j*16+m16, row=quad*4+reg; permuted col=m16*8+j)
        #pragma unroll
        for (int reg = 0; reg < 4; ++reg) {
            int row = rowbase + rs + quad * 4 + reg;
            float part = 0.f;
            ushort8 v;
            #pragma unroll
            for (int j = 0; j < 8; ++j) {
                float x = acc[j][reg];
                part = fmaf(x, av[j], part);
                v[j] = f2bf(x);
            }
            #pragma unroll
            for (int off = 1; off < 16; off <<= 1) part += __shfl_xor(part, off);
            if (row < nrows) {
                *(ushort8*)(Out + (size_t)row * 128 + m16 * 8) = v;
                if (m16 == 0) svec[row] = part;
            }
        }
    }
}

// ---------------- edge pass 1: degree count + per-edge rank ----------------
__global__ void k_count(const int* __restrict__ h, int* __restrict__ count,
                        int* __restrict__ rank, int E) {
    int e = blockIdx.x * blockDim.x + threadIdx.x;
    if (e < E) rank[e] = atomicAdd(count + h[e], 1);
}

// ---------------- hierarchical exclusive scan of count -> rowstart ----------
__device__ __forceinline__ int block_incl_scan256(int s, int* sh, int t) {
    sh[t] = s; __syncthreads();
    #pragma unroll
    for (int off = 1; off < 256; off <<= 1) {
        int x = 0;
        if (t >= off) x = sh[t - off];
        __syncthreads();
        sh[t] += x;
        __syncthreads();
    }
    return sh[t];
}

__global__ __launch_bounds__(256) void k_scan_a(const int* __restrict__ count, int NE,
                                                int* __restrict__ bsum) {
    __shared__ int sh[256];
    int b = blockIdx.x, t = threadIdx.x;
    int base = b * 1024 + t * 4, s = 0;
    #pragma unroll
    for (int j = 0; j < 4; ++j) { int i = base + j; if (i < NE) s += count[i]; }
    sh[t] = s; __syncthreads();
    for (int off = 128; off > 0; off >>= 1) {
        if (t < off) sh[t] += sh[t + off];
        __syncthreads();
    }
    if (t == 0) bsum[b] = sh[0];
}

__global__ __launch_bounds__(256) void k_scan_b(int* __restrict__ bsum, int NB) {
    __shared__ int sh[256];
    int t = threadIdx.x;
    int v[4]; int s = 0;
    #pragma unroll
    for (int j = 0; j < 4; ++j) { int i = t * 4 + j; v[j] = (i < NB) ? bsum[i] : 0; s += v[j]; }
    int incl = block_incl_scan256(s, sh, t);
    int excl = incl - s;
    #pragma unroll
    for (int j = 0; j < 4; ++j) {
        int i = t * 4 + j;
        if (i < NB) { int tmp = v[j]; bsum[i] = excl; excl += tmp; }
    }
}

__global__ __launch_bounds__(256) void k_scan_c(const int* __restrict__ count, int NE,
                                                const int* __restrict__ bsum,
                                                int* __restrict__ rowstart, int E) {
    __shared__ int sh[256];
    int b = blockIdx.x, t = threadIdx.x;
    int base = b * 1024 + t * 4;
    int v[4]; int s = 0;
    #pragma unroll
    for (int j = 0; j < 4; ++j) { int i = base + j; v[j] = (i < NE) ? count[i] : 0; s += v[j]; }
    int incl = block_incl_scan256(s, sh, t);
    int excl = bsum[b] + incl - s;
    #pragma unroll
    for (int j = 0; j < 4; ++j) {
        int i = base + j;
        if (i < NE) { rowstart[i] = excl; excl += v[j]; }
    }
    if (b == 0 && t == 0) rowstart[NE] = E;
}

// ---------------- edge pass 2: score -> exp -> CSR scatter {(r<<17)|t, ev} --
// Atomic-free: rank precomputed in pass 1. No max shift (|score| <~ 6, fp32
// exp safe; softmax shift-invariant). t < 2^17 (NE=100k), r < 2^10 (NR=1000).
__global__ void k_score_scatter(const int* __restrict__ h, const int* __restrict__ r,
                                const int* __restrict__ t, const float* __restrict__ s1,
                                const float* __restrict__ s2, const float* __restrict__ s3,
                                const float* __restrict__ a_b,
                                const int* __restrict__ rowstart, const int* __restrict__ rank,
                                uint2* __restrict__ rt_s, int E) {
    int e = blockIdx.x * blockDim.x + threadIdx.x;
    if (e >= E) return;
    int hi = h[e], ri = r[e], ti = t[e];
    float x = s1[hi] + s2[ri] + s3[ti] + a_b[0];
    float sc = (x >= 0.f) ? x : ALPHA2 * x;
    float ev = __expf(sc);
    rt_s[rowstart[hi] + rank[e]] = make_uint2(((unsigned)ri << 17) | (unsigned)ti,
                                              __float_as_uint(ev));
}

// ---------------- per-entity aggregation: 16 lanes per entity ---------------
// Works in permuted-column space (Pb/Qb/Rb all share the permutation); only
// bias reads and out writes go through the inverse permutation. 4x unrolled
// edge loop -> 8 gathers in flight per 16-lane group.
__global__ __launch_bounds__(256) void k_aggregate(const int* __restrict__ rowstart,
                                                   const uint2* __restrict__ rt_s,
                                                   const unsigned short* __restrict__ Pb,
                                                   const unsigned short* __restrict__ Qb,
                                                   const unsigned short* __restrict__ Rb,
                                                   const float* __restrict__ bias,
                                                   float* __restrict__ out, int NE) {
    int gid = blockIdx.x * blockDim.x + threadIdx.x;
    int n = gid >> 4;        // entity
    int sl = gid & 15;       // sublane: covers permuted cols sl*8..sl*8+7
    if (n >= NE) return;
    int start = rowstart[n], end = rowstart[n + 1];
    int c0 = sl * 8;
    float acc[8] = {};
    float evsum = 0.f;
    int i = start;
    for (; i + 4 <= end; i += 4) {
        uint2 m0 = rt_s[i], m1 = rt_s[i + 1], m2 = rt_s[i + 2], m3 = rt_s[i + 3];
        float ev0 = __uint_as_float(m0.y), ev1 = __uint_as_float(m1.y);
        float ev2 = __uint_as_float(m2.y), ev3 = __uint_as_float(m3.y);
        ushort8 q0 = *(const ushort8*)(Qb + (size_t)(m0.x & 0x1FFFFu) * 128 + c0);
        ushort8 rr0 = *(const ushort8*)(Rb + (size_t)(m0.x >> 17) * 128 + c0);
        ushort8 q1 = *(const ushort8*)(Qb + (size_t)(m1.x & 0x1FFFFu) * 128 + c0);
        ushort8 rr1 = *(const ushort8*)(Rb + (size_t)(m1.x >> 17) * 128 + c0);
        ushort8 q2 = *(const ushort8*)(Qb + (size_t)(m2.x & 0x1FFFFu) * 128 + c0);
        ushort8 rr2 = *(const ushort8*)(Rb + (size_t)(m2.x >> 17) * 128 + c0);
        ushort8 q3 = *(const ushort8*)(Qb + (size_t)(m3.x & 0x1FFFFu) * 128 + c0);
        ushort8 rr3 = *(const ushort8*)(Rb + (size_t)(m3.x >> 17) * 128 + c0);
        evsum += (ev0 + ev1) + (ev2 + ev3);
        #pragma unroll
        for (int j = 0; j < 8; ++j) {
            acc[j] = fmaf(ev0, bf2f(q0[j]) + bf2f(rr0[j]), acc[j]);
            acc[j] = fmaf(ev1, bf2f(q1[j]) + bf2f(rr1[j]), acc[j]);
            acc[j] = fmaf(ev2, bf2f(q2[j]) + bf2f(rr2[j]), acc[j]);
            acc[j] = fmaf(ev3, bf2f(q3[j]) + bf2f(rr3[j]), acc[j]);
        }
    }
    for (; i < end; ++i) {
        uint2 m0 = rt_s[i];
        float ev0 = __uint_as_float(m0.y);
        ushort8 q0 = *(const ushort8*)(Qb + (size_t)(m0.x & 0x1FFFFu) * 128 + c0);
        ushort8 rr0 = *(const ushort8*)(Rb + (size_t)(m0.x >> 17) * 128 + c0);
        evsum += ev0;
        #pragma unroll
        for (int j = 0; j < 8; ++j)
            acc[j] = fmaf(ev0, bf2f(q0[j]) + bf2f(rr0[j]), acc[j]);
    }
    // inverse permutation: stored col sl*8+j  <->  canonical col j*16+sl
    float bi[8];
    #pragma unroll
    for (int j = 0; j < 8; ++j) bi[j] = bias[j * 16 + sl];
    float o[8];
    if (end > start) {
        float inv = 1.f / evsum;
        ushort8 pb = *(const ushort8*)(Pb + (size_t)n * 128 + c0);
        #pragma unroll
        for (int j = 0; j < 8; ++j) o[j] = bf2f(pb[j]) + acc[j] * inv + bi[j];
    } else {
        #pragma unroll
        for (int j = 0; j < 8; ++j) o[j] = bi[j];
    }
    #pragma unroll
    for (int j = 0; j < 8; ++j)
        out[(size_t)n * 128 + j * 16 + sl] = fmaxf(o[j], 0.f);
}

// ============================================================================
static inline size_t align_up(size_t x, size_t a) { return (x + a - 1) / a * a; }

extern "C" void kernel_launch(void* const* d_in, const int* in_sizes, int n_in,
                              void* d_out, int out_size, void* d_ws, size_t ws_size,
                              hipStream_t stream) {
    const int* h_index = (const int*)d_in[0];
    const int* r_index = (const int*)d_in[1];
    const int* t_index = (const int*)d_in[2];
    const float* ent = (const float*)d_in[3];
    const float* rel = (const float*)d_in[4];
    const float* W = (const float*)d_in[5];
    const float* a = (const float*)d_in[6];
    const float* a_b = (const float*)d_in[7];
    const float* bias = (const float*)d_in[8];
    float* out = (float*)d_out;

    int E = in_sizes[0];
    int NE = in_sizes[3] / 128;
    int NR = in_sizes[4] / 128;

    char* p = (char*)d_ws;
    auto alloc = [&](size_t bytes) { char* q = p; p += align_up(bytes, 256); return (void*)q; };
    unsigned short* Pb = (unsigned short*)alloc((size_t)NE * 128 * 2);
    unsigned short* Qb = (unsigned short*)alloc((size_t)NE * 128 * 2);
    unsigned short* Rb = (unsigned short*)alloc((size_t)NR * 128 * 2);
    unsigned short* Bfr = (unsigned short*)alloc((size_t)3 * 128 * 128 * 2);
    float* s1 = (float*)alloc((size_t)NE * 4);
    float* s3 = (float*)alloc((size_t)NE * 4);
    float* s2 = (float*)alloc((size_t)NR * 4);
    int* count = (int*)alloc((size_t)NE * 4);
    int* rowstart = (int*)alloc((size_t)(NE + 1) * 4);
    int* rank = (int*)alloc((size_t)E * 4);
    int NB = (NE + 1023) / 1024;
    int* bsum = (int*)alloc((size_t)NB * 4);
    uint2* rt_s = (uint2*)alloc((size_t)E * 8);
    (void)ws_size; (void)n_in; (void)out_size;

    // 1. prep: W -> fragment-ordered bf16 + zero counters
    int nprep = (NE > 3 * 128 * 128) ? NE : 3 * 128 * 128;
    k_prep<<<(nprep + 255) / 256, 256, 0, stream>>>(W, Bfr, count, NE);
    // 2. edge pass 1: degree count + rank (independent of GEMMs)
    k_count<<<(E + 255) / 256, 256, 0, stream>>>(h_index, count, rank, E);
    // 3. all three GEMMs in one dispatch (64-row tiles, pipelined B loads)
    int NBent = (NE + 63) / 64, NBrel = (NR + 63) / 64;
    k_gemm_all<<<NBent + NBrel, 256, 0, stream>>>(ent, rel, Bfr, Pb, Qb, Rb,
                                                  s1, s3, s2, a, NE, NR, NBent);
    // 4-6. scan -> rowstart
    k_scan_a<<<NB, 256, 0, stream>>>(count, NE, bsum);
    k_scan_b<<<1, 256, 0, stream>>>(bsum, NB);
    k_scan_c<<<NB, 256, 0, stream>>>(count, NE, bsum, rowstart, E);
    // 7. edge pass 2: score -> exp -> CSR scatter (atomic-free, packed 8B)
    k_score_scatter<<<(E + 255) / 256, 256, 0, stream>>>(h_index, r_index, t_index,
                                                         s1, s2, s3, a_b, rowstart,
                                                         rank, rt_s, E);
    // 8. aggregate + bias + relu (16 lanes/entity, denom in-register)
    k_aggregate<<<(NE * 16 + 255) / 256, 256, 0, stream>>>(rowstart, rt_s, Pb, Qb, Rb,
                                                           bias, out, NE);
}